// Round 3
// baseline (258.994 us; speedup 1.0000x reference)
//
#include <hip/hip_runtime.h>
#include <hip/hip_bf16.h>
#include <math.h>

#define BATCH 8
#define TDIM 4096
#define SDIM 1024
#define CDIM 512   // AUDIO_DIM
#define DDIM 768   // SEM_DIM
#define ADIM 128   // ATTN_DIM

typedef short s8v __attribute__((ext_vector_type(8)));   // 8 bf16 (4 VGPRs)
typedef float f4v __attribute__((ext_vector_type(4)));   // 4 fp32 acc

__device__ __forceinline__ short f2bf(float f) {
    unsigned u = __float_as_uint(f);
    u += 0x7fffu + ((u >> 16) & 1u);   // RNE
    return (short)(u >> 16);
}
__device__ __forceinline__ float bf2f(short s) {
    return __uint_as_float(((unsigned)(unsigned short)s) << 16);
}
__device__ __forceinline__ f4v mfma16(s8v a, s8v b, f4v c) {
    return __builtin_amdgcn_mfma_f32_16x16x32_bf16(a, b, c, 0, 0, 0);
}

// ---------------------------------------------------------------------------
// prep_w: transpose weights to bf16 [n][k]; fold ln weight into Wq
// (LN commutes through the linear layer):
//   WqT'[a][c] = lnw[c] * Wq[c][a]
//   uv[0:128]  = sum_c lnb[c] * Wq[c][a]   (u)
//   uv[128:256]= sum_c lnw[c] * Wq[c][a]   (v)
// uv must be zeroed before launch (hipMemsetAsync in kernel_launch).
// ---------------------------------------------------------------------------
__global__ __launch_bounds__(256) void prep_w(
    const float* __restrict__ Wq, const float* __restrict__ Wk,
    const float* __restrict__ Wv, const float* __restrict__ Wo,
    const float* __restrict__ lnw, const float* __restrict__ lnb,
    short* __restrict__ WqT, short* __restrict__ WkT,
    short* __restrict__ WvT, short* __restrict__ WoT,
    float* __restrict__ uv)
{
    int tid = threadIdx.x;
    int gid = blockIdx.x * 256 + tid;
    {
        int k = gid >> 7, n = gid & 127;        // Wq: 512*128, scale by lnw[c]
        WqT[n * 512 + k] = f2bf(Wq[gid] * lnw[k]);
    }
    #pragma unroll
    for (int i = 0; i < 2; ++i) {               // Wk/Wv: 768*128
        int e = gid + i * 65536;
        if (e < 98304) {
            int k = e >> 7, n = e & 127;
            WkT[n * 768 + k] = f2bf(Wk[e]);
            WvT[n * 768 + k] = f2bf(Wv[e]);
        }
    }
    {
        int k = gid >> 9, c = gid & 511;        // Wo: 128*512
        WoT[c * 128 + k] = f2bf(Wo[gid]);
    }
    if (blockIdx.x < 32) {                      // u,v partial reductions
        int a = tid & 127, half = tid >> 7;
        float pu = 0.f, pv = 0.f;
        #pragma unroll
        for (int cc = 0; cc < 8; ++cc) {
            int c = blockIdx.x * 16 + half * 8 + cc;
            float wq = Wq[c * 128 + a];
            pu += lnb[c] * wq;
            pv += lnw[c] * wq;
        }
        atomicAdd(&uv[a], pu);
        atomicAdd(&uv[128 + a], pv);
    }
}

// ---------------------------------------------------------------------------
// kv_proj: K = sem @ Wk + bk -> Kb [b][s][a];  V -> Vb [b][a][s] (transposed)
// ---------------------------------------------------------------------------
__global__ __launch_bounds__(256) void kv_proj(
    const float* __restrict__ sem,
    const short* __restrict__ WkT, const float* __restrict__ bk,
    const short* __restrict__ WvT, const float* __restrict__ bv,
    short* __restrict__ Kb, short* __restrict__ Vb)
{
    __shared__ __align__(16) short sA[32 * 40];      // [row][k32 + pad8]
    __shared__ __align__(16) short sW[2][128 * 40];  // [K/V][n][k32 + pad8]
    const int tid = threadIdx.x, lane = tid & 63, wave = tid >> 6;
    const int ln15 = lane & 15, q = lane >> 4, kq = q * 8;
    const int r0 = blockIdx.x * 32;
    const int b = r0 >> 10, sbase = r0 & 1023;
    const int kv = wave >> 1;        // 0 = K, 1 = V
    const int mh = wave & 1;
    const int m  = mh * 16 + ln15;

    f4v acc[8];
    #pragma unroll
    for (int j = 0; j < 8; ++j) acc[j] = (f4v)0.0f;

    const int srow = tid >> 3;          // 0..31
    const int sk4  = (tid & 7) * 4;     // 0,4,..,28

    for (int kc = 0; kc < DDIM / 32; ++kc) {
        __syncthreads();
        {   // stage sem tile [32][32] fp32 -> bf16
            float4 f = *(const float4*)&sem[(size_t)(r0 + srow) * DDIM + kc * 32 + sk4];
            uint2 pk;
            pk.x = (unsigned short)f2bf(f.x) | ((unsigned)(unsigned short)f2bf(f.y) << 16);
            pk.y = (unsigned short)f2bf(f.z) | ((unsigned)(unsigned short)f2bf(f.w) << 16);
            *(uint2*)&sA[srow * 40 + sk4] = pk;
        }
        #pragma unroll
        for (int i = 0; i < 2; ++i) {   // stage Wk/Wv chunks [128][32]
            int idx8 = i * 256 + tid;
            int n = idx8 >> 2, k8 = (idx8 & 3) * 8;
            *(s8v*)&sW[0][n * 40 + k8] = *(const s8v*)&WkT[(size_t)n * 768 + kc * 32 + k8];
            *(s8v*)&sW[1][n * 40 + k8] = *(const s8v*)&WvT[(size_t)n * 768 + kc * 32 + k8];
        }
        __syncthreads();
        s8v a = *(const s8v*)&sA[m * 40 + kq];
        #pragma unroll
        for (int j = 0; j < 8; ++j) {
            s8v bb = *(const s8v*)&sW[kv][(j * 16 + ln15) * 40 + kq];
            acc[j] = mfma16(a, bb, acc[j]);
        }
    }
    const int s_in_b = sbase + mh * 16 + q * 4;
    if (kv == 0) {
        #pragma unroll
        for (int j = 0; j < 8; ++j) {
            int col = j * 16 + ln15;
            float bias = bk[col];
            #pragma unroll
            for (int r = 0; r < 4; ++r)
                Kb[((size_t)b * SDIM + s_in_b + r) * ADIM + col] = f2bf(acc[j][r] + bias);
        }
    } else {
        #pragma unroll
        for (int j = 0; j < 8; ++j) {
            int col = j * 16 + ln15;
            float bias = bv[col];
            uint2 pk;
            pk.x = (unsigned short)f2bf(acc[j][0] + bias) | ((unsigned)(unsigned short)f2bf(acc[j][1] + bias) << 16);
            pk.y = (unsigned short)f2bf(acc[j][2] + bias) | ((unsigned)(unsigned short)f2bf(acc[j][3] + bias) << 16);
            *(uint2*)&Vb[((size_t)b * ADIM + col) * SDIM + s_in_b] = pk;
        }
    }
}

// ---------------------------------------------------------------------------
// ln_q: Q[t][a] = rs[t]*(x[t,:] @ WqT') + u[a] + bq[a] - mu[t]*rs[t]*v[a]
// Single read of x: fp32 stats in registers + raw bf16 -> swizzled LDS via
// 4x4 micro-transpose and packed ds_write_b64. No normalize pass (LN folded
// into weights / epilogue affine). sWq register-prefetched, stride 76.
// xt swizzle: elem (t,c) at t*512 + (((c>>3) ^ ((t>>2)&7))<<3) + (c&7)
// ---------------------------------------------------------------------------
__global__ __launch_bounds__(256) void ln_q(
    const float* __restrict__ x,
    const short* __restrict__ WqT,   // lnw-scaled, [a][c]
    const float* __restrict__ bq,
    const float* __restrict__ uv,    // u[128], v[128]
    short* __restrict__ Qb)
{
    __shared__ __align__(16) short xt[32 * 512];        // 32 KB swizzled [t][c]
    __shared__ __align__(16) char  ubuf[128 * 76 * 2];  // sWq / red union (19456 B)
    __shared__ float smu[32], srs[32];
    short* sWq  = (short*)ubuf;              // [n][k64 + pad12], stride 76
    float* red1 = (float*)ubuf;              // [32][33]
    float* red2 = (float*)(ubuf + 4224);     // [32][33]
    const int tid = threadIdx.x, lane = tid & 63, wave = tid >> 6;
    const int ln15 = lane & 15, q = lane >> 4, kq = q * 8;
    const int b = blockIdx.x >> 7;
    const int t0 = (blockIdx.x & 127) * 32;
    const float* xb = x + (size_t)b * CDIM * TDIM;

    // Pass A: read x once; stats in fp32; 4x4 micro-transpose -> packed LDS
    const int tq  = (tid & 7) * 4;           // t-quad base; rot = (t>>2)&7 = tid&7
    const int cb  = tid >> 3;                // 0..31
    const int rot = tid & 7;
    float ps1[4] = {0.f,0.f,0.f,0.f}, ps2[4] = {0.f,0.f,0.f,0.f};
    #pragma unroll
    for (int i = 0; i < 4; ++i) {
        float4 f[4];
        #pragma unroll
        for (int jc = 0; jc < 4; ++jc)
            f[jc] = *(const float4*)&xb[(size_t)(i * 128 + cb * 4 + jc) * TDIM + t0 + tq];
        const int c4 = i * 128 + cb * 4;
        const int blockX = ((c4 >> 3) ^ rot);
        const int offs = c4 & 7;             // 0 or 4
        #pragma unroll
        for (int jj = 0; jj < 4; ++jj) {     // jj = t sub-index
            float v0 = ((const float*)&f[0])[jj];
            float v1 = ((const float*)&f[1])[jj];
            float v2 = ((const float*)&f[2])[jj];
            float v3 = ((const float*)&f[3])[jj];
            ps1[jj] += (v0 + v1) + (v2 + v3);
            ps2[jj] += (v0*v0 + v1*v1) + (v2*v2 + v3*v3);
            uint2 pk;
            pk.x = (unsigned short)f2bf(v0) | ((unsigned)(unsigned short)f2bf(v1) << 16);
            pk.y = (unsigned short)f2bf(v2) | ((unsigned)(unsigned short)f2bf(v3) << 16);
            *(uint2*)&xt[(tq + jj) * 512 + blockX * 8 + offs] = pk;
        }
    }
    #pragma unroll
    for (int jj = 0; jj < 4; ++jj) {
        red1[(tq + jj) * 33 + cb] = ps1[jj];
        red2[(tq + jj) * 33 + cb] = ps2[jj];
    }
    __syncthreads();
    if (tid < 32) {
        float s1 = 0.f, s2 = 0.f;
        #pragma unroll 8
        for (int gg = 0; gg < 32; ++gg) { s1 += red1[tid * 33 + gg]; s2 += red2[tid * 33 + gg]; }
        float mu = s1 * (1.f / 512.f);
        float var = s2 * (1.f / 512.f) - mu * mu;
        smu[tid] = mu; srs[tid] = rsqrtf(var + 1e-5f);
    }

    // GEMM: raw-x @ WqT' with register-prefetched staging
    f4v acc[4];
    #pragma unroll
    for (int j = 0; j < 4; ++j) acc[j] = (f4v)0.0f;
    const int mrow = (wave & 1) * 16 + ln15;
    const int jb = (wave >> 1) * 4;
    const int mr_rot = (mrow >> 2) & 7;
    s8v wreg[4];
    #pragma unroll
    for (int i = 0; i < 4; ++i) {
        int idx8 = i * 256 + tid;
        wreg[i] = *(const s8v*)&WqT[(size_t)(idx8 >> 3) * 512 + (idx8 & 7) * 8];
    }
    for (int kc = 0; kc < 8; ++kc) {
        __syncthreads();   // prev MFMA reads done (kc=0: red reads done)
        #pragma unroll
        for (int i = 0; i < 4; ++i) {
            int idx8 = i * 256 + tid;
            *(s8v*)&sWq[(idx8 >> 3) * 76 + (idx8 & 7) * 8] = wreg[i];
        }
        if (kc < 7) {
            #pragma unroll
            for (int i = 0; i < 4; ++i) {
                int idx8 = i * 256 + tid;
                wreg[i] = *(const s8v*)&WqT[(size_t)(idx8 >> 3) * 512 + (kc + 1) * 64 + (idx8 & 7) * 8];
            }
        }
        __syncthreads();
        #pragma unroll
        for (int kk = 0; kk < 2; ++kk) {
            int kb = kc * 8 + kk * 4 + q;
            s8v a = *(const s8v*)&xt[mrow * 512 + ((kb ^ mr_rot) << 3)];
            #pragma unroll
            for (int j = 0; j < 4; ++j) {
                s8v bb = *(const s8v*)&sWq[((jb + j) * 16 + ln15) * 76 + kk * 32 + kq];
                acc[j] = mfma16(a, bb, acc[j]);
            }
        }
    }
    const float scale = 0.08838834764831845f;  // 1/sqrt(128)
    #pragma unroll
    for (int j = 0; j < 4; ++j) {
        int col = (jb + j) * 16 + ln15;
        float uu = uv[col] + bq[col];
        float vv = uv[128 + col];
        #pragma unroll
        for (int r = 0; r < 4; ++r) {
            int tl = (wave & 1) * 16 + q * 4 + r;
            float qv = srs[tl] * acc[j][r] + uu - smu[tl] * srs[tl] * vv;
            Qb[((size_t)b * TDIM + t0 + tl) * ADIM + col] = f2bf(qv * scale);
        }
    }
}

// ---------------------------------------------------------------------------
// attn: flash-style, no max subtraction. Q frags in registers; XOR-swizzled
// LDS; double-buffered K/V with register prefetch; row-sums via MFMA-ones.
// ---------------------------------------------------------------------------
__global__ __launch_bounds__(256) void attn(
    const short* __restrict__ Qb, const short* __restrict__ Kb,
    const short* __restrict__ Vb, short* __restrict__ Cx)
{
    __shared__ __align__(16) short sK [2][64 * 128];  // [s][a]  kb ^= row&15
    __shared__ __align__(16) short sVT[2][128 * 64];  // [a][s]  kb ^= row&7
    __shared__ __align__(16) short sP [64 * 64];      // [t][s]  wave-private rows
    const int tid = threadIdx.x, lane = tid & 63, wave = tid >> 6;
    const int ln15 = lane & 15, q = lane >> 4, kq = q * 8;
    const int b = blockIdx.x >> 6;
    const int t0 = (blockIdx.x & 63) * 64;
    const int m = wave * 16 + ln15;

    const int krow = tid >> 4, kkb = tid & 15;
    const int varow = tid >> 3, vkb = tid & 7;

    s8v qf[4];
    {
        const short* qp = Qb + ((size_t)b * TDIM + t0 + m) * ADIM + kq;
        #pragma unroll
        for (int kc = 0; kc < 4; ++kc) qf[kc] = *(const s8v*)(qp + kc * 32);
    }
    s8v ones;
    #pragma unroll
    for (int j = 0; j < 8; ++j) ones[j] = (short)0x3F80;  // bf16 1.0

    f4v accO[8]; f4v accL = (f4v)0.0f;
    #pragma unroll
    for (int j = 0; j < 8; ++j) accO[j] = (f4v)0.0f;

    const short* Kbase = Kb + (size_t)b * SDIM * ADIM;
    const short* Vbase = Vb + (size_t)b * ADIM * SDIM;
    s8v rk[4], rv[4];

    #pragma unroll
    for (int i = 0; i < 4; ++i) {
        rk[i] = *(const s8v*)(Kbase + (size_t)(i * 16 + krow) * ADIM + kkb * 8);
        rv[i] = *(const s8v*)(Vbase + (size_t)(i * 32 + varow) * SDIM + vkb * 8);
    }
    #pragma unroll
    for (int i = 0; i < 4; ++i) {
        int r = i * 16 + krow;
        *(s8v*)&sK[0][r * 128 + ((kkb ^ (r & 15)) * 8)] = rk[i];
        int a = i * 32 + varow;
        *(s8v*)&sVT[0][a * 64 + ((vkb ^ (a & 7)) * 8)] = rv[i];
    }
    __syncthreads();

    for (int sc = 0; sc < SDIM / 64; ++sc) {
        const int cur = sc & 1;
        if (sc < 15) {
            const int s0n = (sc + 1) * 64;
            #pragma unroll
            for (int i = 0; i < 4; ++i) {
                rk[i] = *(const s8v*)(Kbase + (size_t)(s0n + i * 16 + krow) * ADIM + kkb * 8);
                rv[i] = *(const s8v*)(Vbase + (size_t)(i * 32 + varow) * SDIM + s0n + vkb * 8);
            }
        }
        #pragma unroll
        for (int j = 0; j < 4; ++j) {
            f4v sacc = (f4v)0.0f;
            const int row = j * 16 + ln15;
            #pragma unroll
            for (int kc = 0; kc < 4; ++kc) {
                s8v bb = *(const s8v*)&sK[cur][row * 128 + (((kc * 4 + q) ^ (row & 15)) * 8)];
                sacc = mfma16(qf[kc], bb, sacc);
            }
            #pragma unroll
            for (int r = 0; r < 4; ++r) {
                float ev = __expf(sacc[r]);
                int prow = wave * 16 + q * 4 + r;
                int pcol = j * 16 + ln15;
                sP[prow * 64 + (((pcol >> 3) ^ (prow & 7)) * 8) + (pcol & 7)] = f2bf(ev);
            }
        }
        #pragma unroll
        for (int kc = 0; kc < 2; ++kc) {
            s8v pa = *(const s8v*)&sP[m * 64 + (((kc * 4 + q) ^ (m & 7)) * 8)];
            accL = mfma16(pa, ones, accL);
            #pragma unroll
            for (int j = 0; j < 8; ++j) {
                int a = j * 16 + ln15;
                s8v bb = *(const s8v*)&sVT[cur][a * 64 + (((kc * 4 + q) ^ (a & 7)) * 8)];
                accO[j] = mfma16(pa, bb, accO[j]);
            }
        }
        if (sc < 15) {
            #pragma unroll
            for (int i = 0; i < 4; ++i) {
                int r = i * 16 + krow;
                *(s8v*)&sK[cur ^ 1][r * 128 + ((kkb ^ (r & 15)) * 8)] = rk[i];
                int a = i * 32 + varow;
                *(s8v*)&sVT[cur ^ 1][a * 64 + ((vkb ^ (a & 7)) * 8)] = rv[i];
            }
        }
        __syncthreads();
    }
    #pragma unroll
    for (int r = 0; r < 4; ++r) {
        float rinv = 1.0f / accL[r];
        int t = t0 + wave * 16 + q * 4 + r;
        #pragma unroll
        for (int j = 0; j < 8; ++j) {
            int col = j * 16 + ln15;
            Cx[((size_t)b * TDIM + t) * ADIM + col] = f2bf(accO[j][r] * rinv);
        }
    }
}

// ---------------------------------------------------------------------------
// out_proj: delta = ctx @ Wo + bo, written transposed [B][C][T] coalesced
// ---------------------------------------------------------------------------
__global__ __launch_bounds__(256) void out_proj(
    const short* __restrict__ Cx, const short* __restrict__ WoT,
    const float* __restrict__ bo, float* __restrict__ out)
{
    __shared__ __align__(16) short sCtx[64 * 136];
    __shared__ __align__(16) char  buf[128 * 136 * 2];
    short* sWoT = (short*)buf;
    float* outT = (float*)buf;
    const int tid = threadIdx.x, lane = tid & 63, wave = tid >> 6;
    const int ln15 = lane & 15, q = lane >> 4, kq = q * 8;
    const int b = blockIdx.x >> 8;
    const int rem = blockIdx.x & 255;
    const int t0 = (rem & 63) * 64;
    const int c0 = (rem >> 6) * 128;

    #pragma unroll
    for (int i = 0; i < 4; ++i) {
        int idx8 = i * 256 + tid;
        int row = idx8 >> 4, a8 = (idx8 & 15) * 8;
        *(s8v*)&sCtx[row * 136 + a8] = *(const s8v*)&Cx[((size_t)b * TDIM + t0 + row) * ADIM + a8];
    }
    #pragma unroll
    for (int i = 0; i < 8; ++i) {
        int idx8 = i * 256 + tid;
        int n = idx8 >> 4, k8 = (idx8 & 15) * 8;
        *(s8v*)&sWoT[n * 136 + k8] = *(const s8v*)&WoT[(size_t)(c0 + n) * ADIM + k8];
    }
    __syncthreads();
    f4v acc[8];
    #pragma unroll
    for (int j = 0; j < 8; ++j) acc[j] = (f4v)0.0f;
    const int m = wave * 16 + ln15;
    #pragma unroll
    for (int kc = 0; kc < 4; ++kc) {
        s8v a = *(const s8v*)&sCtx[m * 136 + kc * 32 + kq];
        #pragma unroll
        for (int j = 0; j < 8; ++j) {
            s8v bb = *(const s8v*)&sWoT[(j * 16 + ln15) * 136 + kc * 32 + kq];
            acc[j] = mfma16(a, bb, acc[j]);
        }
    }
    __syncthreads();
    #pragma unroll
    for (int j = 0; j < 8; ++j) {
        int cl = j * 16 + ln15;
        float bias = bo[c0 + cl];
        #pragma unroll
        for (int r = 0; r < 4; ++r) {
            int tl = wave * 16 + q * 4 + r;
            outT[cl * 68 + tl] = acc[j][r] + bias;
        }
    }
    __syncthreads();
    #pragma unroll
    for (int i = 0; i < 8; ++i) {
        int idx4 = i * 256 + tid;
        int c = idx4 >> 4, t4 = (idx4 & 15) * 4;
        float4 v = *(const float4*)&outT[c * 68 + t4];
        *(float4*)&out[((size_t)b * CDIM + c0 + c) * TDIM + t0 + t4] = v;
    }
}

// ---------------------------------------------------------------------------
extern "C" void kernel_launch(void* const* d_in, const int* in_sizes, int n_in,
                              void* d_out, int out_size, void* d_ws, size_t ws_size,
                              hipStream_t stream) {
    const float* x   = (const float*)d_in[0];
    const float* sem = (const float*)d_in[1];
    const float* lnw = (const float*)d_in[2];
    const float* lnb = (const float*)d_in[3];
    const float* Wq  = (const float*)d_in[4];
    const float* bq  = (const float*)d_in[5];
    const float* Wk  = (const float*)d_in[6];
    const float* bk  = (const float*)d_in[7];
    const float* Wv  = (const float*)d_in[8];
    const float* bv  = (const float*)d_in[9];
    const float* Wo  = (const float*)d_in[10];
    const float* bo  = (const float*)d_in[11];
    float* out = (float*)d_out;

    short* ws  = (short*)d_ws;
    short* Qb  = ws;                                    // [B][T][A]  bf16
    short* Kb  = Qb  + (size_t)BATCH * TDIM * ADIM;     // [B][S][A]
    short* Vb  = Kb  + (size_t)BATCH * SDIM * ADIM;     // [B][A][S]  (transposed)
    short* Cx  = Vb  + (size_t)BATCH * SDIM * ADIM;     // [B][T][A]
    short* WqT = Cx  + (size_t)BATCH * TDIM * ADIM;     // [128][512] (lnw-scaled)
    short* WkT = WqT + 128 * 512;                       // [128][768]
    short* WvT = WkT + 128 * 768;                       // [128][768]
    short* WoT = WvT + 128 * 768;                       // [512][128]
    float* uv  = (float*)(WoT + 512 * 128);             // u[128], v[128]

    hipMemsetAsync(uv, 0, 256 * sizeof(float), stream);
    hipLaunchKernelGGL(prep_w,  dim3(256),  dim3(256), 0, stream,
                       Wq, Wk, Wv, Wo, lnw, lnb, WqT, WkT, WvT, WoT, uv);
    hipLaunchKernelGGL(kv_proj, dim3(256),  dim3(256), 0, stream, sem, WkT, bk, WvT, bv, Kb, Vb);
    hipLaunchKernelGGL(ln_q,    dim3(1024), dim3(256), 0, stream, x, WqT, bq, uv, Qb);
    hipLaunchKernelGGL(attn,    dim3(512),  dim3(256), 0, stream, Qb, Kb, Vb, Cx);
    hipLaunchKernelGGL(out_proj,dim3(2048), dim3(256), 0, stream, Cx, WoT, bo, out);
}

// Round 4
// 241.734 us; speedup vs baseline: 1.0714x; 1.0714x over previous
//
#include <hip/hip_runtime.h>
#include <hip/hip_bf16.h>
#include <math.h>

#define BATCH 8
#define TDIM 4096
#define SDIM 1024
#define CDIM 512   // AUDIO_DIM
#define DDIM 768   // SEM_DIM
#define ADIM 128   // ATTN_DIM

typedef short s8v __attribute__((ext_vector_type(8)));   // 8 bf16 (4 VGPRs)
typedef float f4v __attribute__((ext_vector_type(4)));   // 4 fp32 acc

__device__ __forceinline__ short f2bf(float f) {
    unsigned u = __float_as_uint(f);
    u += 0x7fffu + ((u >> 16) & 1u);   // RNE
    return (short)(u >> 16);
}
__device__ __forceinline__ f4v mfma16(s8v a, s8v b, f4v c) {
    return __builtin_amdgcn_mfma_f32_16x16x32_bf16(a, b, c, 0, 0, 0);
}

// ---------------------------------------------------------------------------
// prep_w: transpose weights to bf16 [n][k]; fold ln weight into Wq:
//   WqT'[a][c] = lnw[c] * Wq[c][a];  uv[a] = lnb@Wq, uv[128+a] = lnw@Wq
// ---------------------------------------------------------------------------
__global__ __launch_bounds__(256) void prep_w(
    const float* __restrict__ Wq, const float* __restrict__ Wk,
    const float* __restrict__ Wv, const float* __restrict__ Wo,
    const float* __restrict__ lnw, const float* __restrict__ lnb,
    short* __restrict__ WqT, short* __restrict__ WkT,
    short* __restrict__ WvT, short* __restrict__ WoT,
    float* __restrict__ uv)
{
    int tid = threadIdx.x;
    int gid = blockIdx.x * 256 + tid;
    {
        int k = gid >> 7, n = gid & 127;        // Wq: 512*128, scale by lnw[c]
        WqT[n * 512 + k] = f2bf(Wq[gid] * lnw[k]);
    }
    #pragma unroll
    for (int i = 0; i < 2; ++i) {               // Wk/Wv: 768*128
        int e = gid + i * 65536;
        if (e < 98304) {
            int k = e >> 7, n = e & 127;
            WkT[n * 768 + k] = f2bf(Wk[e]);
            WvT[n * 768 + k] = f2bf(Wv[e]);
        }
    }
    {
        int k = gid >> 9, c = gid & 511;        // Wo: 128*512
        WoT[c * 128 + k] = f2bf(Wo[gid]);
    }
    if (blockIdx.x < 32) {                      // u,v partial reductions
        int a = tid & 127, half = tid >> 7;
        float pu = 0.f, pv = 0.f;
        #pragma unroll
        for (int cc = 0; cc < 8; ++cc) {
            int c = blockIdx.x * 16 + half * 8 + cc;
            float wq = Wq[c * 128 + a];
            pu += lnb[c] * wq;
            pv += lnw[c] * wq;
        }
        atomicAdd(&uv[a], pu);
        atomicAdd(&uv[128 + a], pv);
    }
}

// ---------------------------------------------------------------------------
// kv_proj: K = sem @ Wk + bk -> Kb [b][s][a];  V -> Vb [b][a][s] (transposed)
// ---------------------------------------------------------------------------
__global__ __launch_bounds__(256) void kv_proj(
    const float* __restrict__ sem,
    const short* __restrict__ WkT, const float* __restrict__ bk,
    const short* __restrict__ WvT, const float* __restrict__ bv,
    short* __restrict__ Kb, short* __restrict__ Vb)
{
    __shared__ __align__(16) short sA[32 * 40];      // [row][k32 + pad8]
    __shared__ __align__(16) short sW[2][128 * 40];  // [K/V][n][k32 + pad8]
    const int tid = threadIdx.x, lane = tid & 63, wave = tid >> 6;
    const int ln15 = lane & 15, q = lane >> 4, kq = q * 8;
    const int r0 = blockIdx.x * 32;
    const int b = r0 >> 10, sbase = r0 & 1023;
    const int kv = wave >> 1;        // 0 = K, 1 = V
    const int mh = wave & 1;
    const int m  = mh * 16 + ln15;

    f4v acc[8];
    #pragma unroll
    for (int j = 0; j < 8; ++j) acc[j] = (f4v)0.0f;

    const int srow = tid >> 3;          // 0..31
    const int sk4  = (tid & 7) * 4;     // 0,4,..,28

    for (int kc = 0; kc < DDIM / 32; ++kc) {
        __syncthreads();
        {   // stage sem tile [32][32] fp32 -> bf16
            float4 f = *(const float4*)&sem[(size_t)(r0 + srow) * DDIM + kc * 32 + sk4];
            uint2 pk;
            pk.x = (unsigned short)f2bf(f.x) | ((unsigned)(unsigned short)f2bf(f.y) << 16);
            pk.y = (unsigned short)f2bf(f.z) | ((unsigned)(unsigned short)f2bf(f.w) << 16);
            *(uint2*)&sA[srow * 40 + sk4] = pk;
        }
        #pragma unroll
        for (int i = 0; i < 2; ++i) {   // stage Wk/Wv chunks [128][32]
            int idx8 = i * 256 + tid;
            int n = idx8 >> 2, k8 = (idx8 & 3) * 8;
            *(s8v*)&sW[0][n * 40 + k8] = *(const s8v*)&WkT[(size_t)n * 768 + kc * 32 + k8];
            *(s8v*)&sW[1][n * 40 + k8] = *(const s8v*)&WvT[(size_t)n * 768 + kc * 32 + k8];
        }
        __syncthreads();
        s8v a = *(const s8v*)&sA[m * 40 + kq];
        #pragma unroll
        for (int j = 0; j < 8; ++j) {
            s8v bb = *(const s8v*)&sW[kv][(j * 16 + ln15) * 40 + kq];
            acc[j] = mfma16(a, bb, acc[j]);
        }
    }
    const int s_in_b = sbase + mh * 16 + q * 4;
    if (kv == 0) {
        #pragma unroll
        for (int j = 0; j < 8; ++j) {
            int col = j * 16 + ln15;
            float bias = bk[col];
            #pragma unroll
            for (int r = 0; r < 4; ++r)
                Kb[((size_t)b * SDIM + s_in_b + r) * ADIM + col] = f2bf(acc[j][r] + bias);
        }
    } else {
        #pragma unroll
        for (int j = 0; j < 8; ++j) {
            int col = j * 16 + ln15;
            float bias = bv[col];
            uint2 pk;
            pk.x = (unsigned short)f2bf(acc[j][0] + bias) | ((unsigned)(unsigned short)f2bf(acc[j][1] + bias) << 16);
            pk.y = (unsigned short)f2bf(acc[j][2] + bias) | ((unsigned)(unsigned short)f2bf(acc[j][3] + bias) << 16);
            *(uint2*)&Vb[((size_t)b * ADIM + col) * SDIM + s_in_b] = pk;
        }
    }
}

// ---------------------------------------------------------------------------
// ln_q v2: Q[t][a] = rs[t]*(x[t,:] @ WqT') + u[a]+bq[a] - mu[t]*rs[t]*v[a]
// Barrier-free K-loop: B-frags (Wq) loaded 16B-contiguous straight from
// global (WqT is 128 KB, L2-resident) -- no sWq staging, no K-loop barriers.
// LDS only holds the x transpose (written once, XOR swizzle rot=((t>>1)^(t>>3))&7,
// balanced 8 lanes/4-bank-group for both b128 writes and A-frag reads) and
// the stats reduction. 2 barriers total. LDS ~41.5 KB -> 3 blocks/CU.
// ---------------------------------------------------------------------------
__global__ __launch_bounds__(256) void ln_q(
    const float* __restrict__ x,
    const short* __restrict__ WqT,   // lnw-scaled, [a][c]
    const float* __restrict__ bq,
    const float* __restrict__ uv,    // u[128], v[128]
    short* __restrict__ Qb)
{
    __shared__ __align__(16) short xt[32 * 512];    // 32 KB, swizzled [t][c]
    __shared__ float red1[32][33], red2[32][33];    // 8.4 KB
    __shared__ float smu[32], srs[32];
    const int tid = threadIdx.x, lane = tid & 63, wave = tid >> 6;
    const int ln15 = lane & 15, q = lane >> 4;
    const int b = blockIdx.x >> 7;
    const int t0 = (blockIdx.x & 127) * 32;
    const float* xb = x + (size_t)b * CDIM * TDIM;

    // Pass A: 16 independent float4 loads/thread (max MLP), fp32 stats,
    // 4x8 micro-transpose -> ds_write_b128 into swizzled xt.
    const int tq = tid & 7;        // t-quad 0..7
    const int cg = tid >> 3;       // 0..31 (c-group of 16)
    float ps1[4] = {0.f,0.f,0.f,0.f}, ps2[4] = {0.f,0.f,0.f,0.f};
    #pragma unroll
    for (int g8 = 0; g8 < 2; ++g8) {
        float4 f[8];
        #pragma unroll
        for (int cc = 0; cc < 8; ++cc)
            f[cc] = *(const float4*)&xb[(size_t)(cg * 16 + g8 * 8 + cc) * TDIM + t0 + tq * 4];
        const int cb = cg * 2 + g8;     // c-block of 8 (0..63)
        #pragma unroll
        for (int jj = 0; jj < 4; ++jj) {
            const int t = tq * 4 + jj;
            const int rot = ((t >> 1) ^ (t >> 3)) & 7;
            s8v v;
            #pragma unroll
            for (int cc = 0; cc < 8; ++cc) {
                float val = ((const float*)&f[cc])[jj];
                ps1[jj] += val; ps2[jj] += val * val;
                v[cc] = f2bf(val);
            }
            *(s8v*)&xt[t * 512 + ((cb ^ rot) * 8)] = v;
        }
    }
    #pragma unroll
    for (int jj = 0; jj < 4; ++jj) {
        red1[tq * 4 + jj][cg] = ps1[jj];
        red2[tq * 4 + jj][cg] = ps2[jj];
    }
    __syncthreads();
    if (tid < 32) {
        float s1 = 0.f, s2 = 0.f;
        #pragma unroll 8
        for (int g = 0; g < 32; ++g) { s1 += red1[tid][g]; s2 += red2[tid][g]; }
        float mu = s1 * (1.f / 512.f);
        float var = s2 * (1.f / 512.f) - mu * mu;
        smu[tid] = mu; srs[tid] = rsqrtf(var + 1e-5f);
    }
    __syncthreads();

    // Barrier-free GEMM: M=32, per-wave N=32 (2 n-frags), K=512 (16 kk-steps)
    f4v acc[2][2];
    #pragma unroll
    for (int jm = 0; jm < 2; ++jm)
        #pragma unroll
        for (int jn = 0; jn < 2; ++jn) acc[jm][jn] = (f4v)0.0f;
    const short* wp = WqT + (size_t)(wave * 32 + ln15) * 512 + q * 8;
    #pragma unroll 4
    for (int kk = 0; kk < 16; ++kk) {
        s8v bfr[2], afr[2];
        #pragma unroll
        for (int jn = 0; jn < 2; ++jn)
            bfr[jn] = *(const s8v*)(wp + jn * 16 * 512 + kk * 32);
        #pragma unroll
        for (int jm = 0; jm < 2; ++jm) {
            const int t = jm * 16 + ln15;
            const int rot = ((t >> 1) ^ (t >> 3)) & 7;
            afr[jm] = *(const s8v*)&xt[t * 512 + (((kk * 4 + q) ^ rot) * 8)];
        }
        #pragma unroll
        for (int jm = 0; jm < 2; ++jm)
            #pragma unroll
            for (int jn = 0; jn < 2; ++jn)
                acc[jm][jn] = mfma16(afr[jm], bfr[jn], acc[jm][jn]);
    }
    const float scale = 0.08838834764831845f;  // 1/sqrt(128)
    #pragma unroll
    for (int jn = 0; jn < 2; ++jn) {
        const int col = wave * 32 + jn * 16 + ln15;
        const float uu = uv[col] + bq[col];
        const float vv = uv[128 + col];
        #pragma unroll
        for (int jm = 0; jm < 2; ++jm) {
            #pragma unroll
            for (int r = 0; r < 4; ++r) {
                const int tl = jm * 16 + q * 4 + r;
                float qv = srs[tl] * acc[jm][jn][r] + uu - smu[tl] * srs[tl] * vv;
                Qb[((size_t)b * TDIM + t0 + tl) * ADIM + col] = f2bf(qv * scale);
            }
        }
    }
}

// ---------------------------------------------------------------------------
// attn: flash-style, no max subtraction. Q frags in registers; XOR-swizzled
// LDS; double-buffered K/V with register prefetch; row-sums via MFMA-ones.
// ---------------------------------------------------------------------------
__global__ __launch_bounds__(256) void attn(
    const short* __restrict__ Qb, const short* __restrict__ Kb,
    const short* __restrict__ Vb, short* __restrict__ Cx)
{
    __shared__ __align__(16) short sK [2][64 * 128];  // [s][a]  kb ^= row&15
    __shared__ __align__(16) short sVT[2][128 * 64];  // [a][s]  kb ^= row&7
    __shared__ __align__(16) short sP [64 * 64];      // [t][s]  wave-private rows
    const int tid = threadIdx.x, lane = tid & 63, wave = tid >> 6;
    const int ln15 = lane & 15, q = lane >> 4, kq = q * 8;
    const int b = blockIdx.x >> 6;
    const int t0 = (blockIdx.x & 63) * 64;
    const int m = wave * 16 + ln15;

    const int krow = tid >> 4, kkb = tid & 15;
    const int varow = tid >> 3, vkb = tid & 7;

    s8v qf[4];
    {
        const short* qp = Qb + ((size_t)b * TDIM + t0 + m) * ADIM + kq;
        #pragma unroll
        for (int kc = 0; kc < 4; ++kc) qf[kc] = *(const s8v*)(qp + kc * 32);
    }
    s8v ones;
    #pragma unroll
    for (int j = 0; j < 8; ++j) ones[j] = (short)0x3F80;  // bf16 1.0

    f4v accO[8]; f4v accL = (f4v)0.0f;
    #pragma unroll
    for (int j = 0; j < 8; ++j) accO[j] = (f4v)0.0f;

    const short* Kbase = Kb + (size_t)b * SDIM * ADIM;
    const short* Vbase = Vb + (size_t)b * ADIM * SDIM;
    s8v rk[4], rv[4];

    #pragma unroll
    for (int i = 0; i < 4; ++i) {
        rk[i] = *(const s8v*)(Kbase + (size_t)(i * 16 + krow) * ADIM + kkb * 8);
        rv[i] = *(const s8v*)(Vbase + (size_t)(i * 32 + varow) * SDIM + vkb * 8);
    }
    #pragma unroll
    for (int i = 0; i < 4; ++i) {
        int r = i * 16 + krow;
        *(s8v*)&sK[0][r * 128 + ((kkb ^ (r & 15)) * 8)] = rk[i];
        int a = i * 32 + varow;
        *(s8v*)&sVT[0][a * 64 + ((vkb ^ (a & 7)) * 8)] = rv[i];
    }
    __syncthreads();

    for (int sc = 0; sc < SDIM / 64; ++sc) {
        const int cur = sc & 1;
        if (sc < 15) {
            const int s0n = (sc + 1) * 64;
            #pragma unroll
            for (int i = 0; i < 4; ++i) {
                rk[i] = *(const s8v*)(Kbase + (size_t)(s0n + i * 16 + krow) * ADIM + kkb * 8);
                rv[i] = *(const s8v*)(Vbase + (size_t)(i * 32 + varow) * SDIM + s0n + vkb * 8);
            }
        }
        #pragma unroll
        for (int j = 0; j < 4; ++j) {
            f4v sacc = (f4v)0.0f;
            const int row = j * 16 + ln15;
            #pragma unroll
            for (int kc = 0; kc < 4; ++kc) {
                s8v bb = *(const s8v*)&sK[cur][row * 128 + (((kc * 4 + q) ^ (row & 15)) * 8)];
                sacc = mfma16(qf[kc], bb, sacc);
            }
            #pragma unroll
            for (int r = 0; r < 4; ++r) {
                float ev = __expf(sacc[r]);
                int prow = wave * 16 + q * 4 + r;
                int pcol = j * 16 + ln15;
                sP[prow * 64 + (((pcol >> 3) ^ (prow & 7)) * 8) + (pcol & 7)] = f2bf(ev);
            }
        }
        #pragma unroll
        for (int kc = 0; kc < 2; ++kc) {
            s8v pa = *(const s8v*)&sP[m * 64 + (((kc * 4 + q) ^ (m & 7)) * 8)];
            accL = mfma16(pa, ones, accL);
            #pragma unroll
            for (int j = 0; j < 8; ++j) {
                int a = j * 16 + ln15;
                s8v bb = *(const s8v*)&sVT[cur][a * 64 + (((kc * 4 + q) ^ (a & 7)) * 8)];
                accO[j] = mfma16(pa, bb, accO[j]);
            }
        }
        if (sc < 15) {
            #pragma unroll
            for (int i = 0; i < 4; ++i) {
                int r = i * 16 + krow;
                *(s8v*)&sK[cur ^ 1][r * 128 + ((kkb ^ (r & 15)) * 8)] = rk[i];
                int a = i * 32 + varow;
                *(s8v*)&sVT[cur ^ 1][a * 64 + ((vkb ^ (a & 7)) * 8)] = rv[i];
            }
        }
        __syncthreads();
    }
    #pragma unroll
    for (int r = 0; r < 4; ++r) {
        float rinv = 1.0f / accL[r];
        int t = t0 + wave * 16 + q * 4 + r;
        #pragma unroll
        for (int j = 0; j < 8; ++j) {
            int col = j * 16 + ln15;
            Cx[((size_t)b * TDIM + t) * ADIM + col] = f2bf(accO[j][r] * rinv);
        }
    }
}

// ---------------------------------------------------------------------------
// out_proj: delta = ctx @ Wo + bo, written transposed [B][C][T] coalesced
// ---------------------------------------------------------------------------
__global__ __launch_bounds__(256) void out_proj(
    const short* __restrict__ Cx, const short* __restrict__ WoT,
    const float* __restrict__ bo, float* __restrict__ out)
{
    __shared__ __align__(16) short sCtx[64 * 136];
    __shared__ __align__(16) char  buf[128 * 136 * 2];
    short* sWoT = (short*)buf;
    float* outT = (float*)buf;
    const int tid = threadIdx.x, lane = tid & 63, wave = tid >> 6;
    const int ln15 = lane & 15, q = lane >> 4, kq = q * 8;
    const int b = blockIdx.x >> 8;
    const int rem = blockIdx.x & 255;
    const int t0 = (rem & 63) * 64;
    const int c0 = (rem >> 6) * 128;

    #pragma unroll
    for (int i = 0; i < 4; ++i) {
        int idx8 = i * 256 + tid;
        int row = idx8 >> 4, a8 = (idx8 & 15) * 8;
        *(s8v*)&sCtx[row * 136 + a8] = *(const s8v*)&Cx[((size_t)b * TDIM + t0 + row) * ADIM + a8];
    }
    #pragma unroll
    for (int i = 0; i < 8; ++i) {
        int idx8 = i * 256 + tid;
        int n = idx8 >> 4, k8 = (idx8 & 15) * 8;
        *(s8v*)&sWoT[n * 136 + k8] = *(const s8v*)&WoT[(size_t)(c0 + n) * ADIM + k8];
    }
    __syncthreads();
    f4v acc[8];
    #pragma unroll
    for (int j = 0; j < 8; ++j) acc[j] = (f4v)0.0f;
    const int m = wave * 16 + ln15;
    #pragma unroll
    for (int kc = 0; kc < 4; ++kc) {
        s8v a = *(const s8v*)&sCtx[m * 136 + kc * 32 + kq];
        #pragma unroll
        for (int j = 0; j < 8; ++j) {
            s8v bb = *(const s8v*)&sWoT[(j * 16 + ln15) * 136 + kc * 32 + kq];
            acc[j] = mfma16(a, bb, acc[j]);
        }
    }
    __syncthreads();
    #pragma unroll
    for (int j = 0; j < 8; ++j) {
        int cl = j * 16 + ln15;
        float bias = bo[c0 + cl];
        #pragma unroll
        for (int r = 0; r < 4; ++r) {
            int tl = wave * 16 + q * 4 + r;
            outT[cl * 68 + tl] = acc[j][r] + bias;
        }
    }
    __syncthreads();
    #pragma unroll
    for (int i = 0; i < 8; ++i) {
        int idx4 = i * 256 + tid;
        int c = idx4 >> 4, t4 = (idx4 & 15) * 4;
        float4 v = *(const float4*)&outT[c * 68 + t4];
        *(float4*)&out[((size_t)b * CDIM + c0 + c) * TDIM + t0 + t4] = v;
    }
}

// ---------------------------------------------------------------------------
extern "C" void kernel_launch(void* const* d_in, const int* in_sizes, int n_in,
                              void* d_out, int out_size, void* d_ws, size_t ws_size,
                              hipStream_t stream) {
    const float* x   = (const float*)d_in[0];
    const float* sem = (const float*)d_in[1];
    const float* lnw = (const float*)d_in[2];
    const float* lnb = (const float*)d_in[3];
    const float* Wq  = (const float*)d_in[4];
    const float* bq  = (const float*)d_in[5];
    const float* Wk  = (const float*)d_in[6];
    const float* bk  = (const float*)d_in[7];
    const float* Wv  = (const float*)d_in[8];
    const float* bv  = (const float*)d_in[9];
    const float* Wo  = (const float*)d_in[10];
    const float* bo  = (const float*)d_in[11];
    float* out = (float*)d_out;

    short* ws  = (short*)d_ws;
    short* Qb  = ws;                                    // [B][T][A]  bf16
    short* Kb  = Qb  + (size_t)BATCH * TDIM * ADIM;     // [B][S][A]
    short* Vb  = Kb  + (size_t)BATCH * SDIM * ADIM;     // [B][A][S]  (transposed)
    short* Cx  = Vb  + (size_t)BATCH * SDIM * ADIM;     // [B][T][A]
    short* WqT = Cx  + (size_t)BATCH * TDIM * ADIM;     // [128][512] (lnw-scaled)
    short* WkT = WqT + 128 * 512;                       // [128][768]
    short* WvT = WkT + 128 * 768;                       // [128][768]
    short* WoT = WvT + 128 * 768;                       // [512][128]
    float* uv  = (float*)(WoT + 512 * 128);             // u[128], v[128]

    hipMemsetAsync(uv, 0, 256 * sizeof(float), stream);
    hipLaunchKernelGGL(prep_w,  dim3(256),  dim3(256), 0, stream,
                       Wq, Wk, Wv, Wo, lnw, lnb, WqT, WkT, WvT, WoT, uv);
    hipLaunchKernelGGL(kv_proj, dim3(256),  dim3(256), 0, stream, sem, WkT, bk, WvT, bv, Kb, Vb);
    hipLaunchKernelGGL(ln_q,    dim3(1024), dim3(256), 0, stream, x, WqT, bq, uv, Qb);
    hipLaunchKernelGGL(attn,    dim3(512),  dim3(256), 0, stream, Qb, Kb, Vb, Cx);
    hipLaunchKernelGGL(out_proj,dim3(2048), dim3(256), 0, stream, Cx, WoT, bo, out);
}